// Round 11
// baseline (283.423 us; speedup 1.0000x reference)
//
#include <hip/hip_runtime.h>
#include <hip/hip_bf16.h>
#include <math.h>

namespace {

constexpr int C = 128;  // channels
constexpr int K = 32;   // max degree

typedef float float4v __attribute__((ext_vector_type(4)));
typedef short short8v __attribute__((ext_vector_type(8)));   // 8 bf16 (4 VGPR)
typedef unsigned short ushort8v __attribute__((ext_vector_type(8)));
typedef int int2v __attribute__((ext_vector_type(2)));

__device__ __forceinline__ float bf2f(unsigned short u) {
    return __uint_as_float(((unsigned int)u) << 16);
}
__device__ __forceinline__ unsigned short f2bf(float x) {
    __hip_bfloat16 h = __float2bfloat16(x);
    return *(unsigned short*)&h;
}

// ---------------------------------------------------------------------------
// Kernel 0: invs[n] = 1/sqrt(1 + #valid neighbors), int4 edge loads + 8-lane
// shfl_xor reduce (32 nodes/block). Side jobs: block 0 zeroes h's padding row
// N; blocks 1..64 split W1 into hi/lo bf16 planes; blocks 65..128 split W2.
// (Pre-splitting W once removes 16K f2bf+sub VALU ops from EVERY gemm block.)
// ---------------------------------------------------------------------------
__global__ __launch_bounds__(256) void deg_kernel(
    const int* __restrict__ edge, float* __restrict__ invs,
    unsigned int* __restrict__ hzero, const float* __restrict__ W1,
    const float* __restrict__ W2, unsigned short* __restrict__ whl, int N) {
    const int bid = blockIdx.x;
    const int t = threadIdx.x;

    if (bid == 0 && t < 64) {
        hzero[(size_t)N * (C / 2) + t] = 0u;  // row N: 128 bf16 zeros
    }
    if (bid >= 1 && bid <= 128) {
        int which = (bid - 1) >> 6;           // 0: W1, 1: W2
        int p = ((bid - 1) & 63) * 256 + t;   // 0..16383
        float w = (which ? W2 : W1)[p];
        unsigned short hb = f2bf(w);
        unsigned short lb = f2bf(w - bf2f(hb));
        unsigned short* dst = whl + (size_t)which * 32768;
        dst[p] = hb;           // hi plane
        dst[16384 + p] = lb;   // lo plane
    }

    int node = bid * 32 + (t >> 3);
    int k4 = (t & 7) * 4;
    int4 e = make_int4(-1, -1, -1, -1);
    if (node < N) e = *(const int4*)(edge + (size_t)node * K + k4);
    int cnt = (e.x >= 0) + (e.y >= 0) + (e.z >= 0) + (e.w >= 0);
    cnt += __shfl_xor(cnt, 1);
    cnt += __shfl_xor(cnt, 2);
    cnt += __shfl_xor(cnt, 4);
    if ((t & 7) == 0 && node < N)
        invs[node] = 1.0f / sqrtf((float)(cnt + 1));
}

// ---------------------------------------------------------------------------
// Kernel 1: H[n][ch] = bf16( (X[n] . W[ch]) * invs[n] ),  H canonical [N+1][128]
// Split-bf16 MFMA GEMM (x@W ~= xh@Wh + xl@Wh + xh@Wl, ~fp32 accuracy).
// W arrives PRE-SPLIT ([2][128][128] bf16) -> LDS staging is a pure vector
// copy (round 10 re-split W per block on the VALU). A-fragments loaded direct
// from global with in-register hi/lo split.
// mfma_f32_16x16x32_bf16 layouts (learn_hip-verified): A/B lane l: row/col =
// l&15, k = (l>>4)*8 + j. C/D: col = l&15, row = (l>>4)*4 + reg.
// ---------------------------------------------------------------------------
__global__ __launch_bounds__(256, 2) void gemm_mfma_kernel(
    const float* __restrict__ X, const unsigned short* __restrict__ Wp,
    const float* __restrict__ invs, unsigned short* __restrict__ H, int N) {
    __shared__ unsigned short Whl[2][C][136];  // [hi/lo][out_ch][in_ch], padded

    const int t = threadIdx.x;
    const int n0 = blockIdx.x * 128;

    // Stage pre-split W planes: 2 x 128 x 16 ushort8 vectors = 4096 / 256 thr.
    for (int p = t; p < 2 * C * 16; p += 256) {
        int seg = p >> 11;
        int rem = p & 2047;
        int row = rem >> 4;
        int v8 = (rem & 15) * 8;
        *(ushort8v*)&Whl[seg][row][v8] =
            *(const ushort8v*)(Wp + (size_t)seg * 16384 + row * 128 + v8);
    }
    __syncthreads();

    const int wv = t >> 6;   // wave 0..3
    const int l = t & 63;
    const int lm = l & 15;   // row (A) / col (B) within 16-tile
    const int lk = l >> 4;   // k-group (x8)
    const int rbase = n0 + wv * 32;

    int rowA0 = rbase + lm;
    int rowA1 = rbase + 16 + lm;
    rowA0 = rowA0 < N ? rowA0 : N - 1;
    rowA1 = rowA1 < N ? rowA1 : N - 1;
    const float* xp0 = X + (size_t)rowA0 * C;
    const float* xp1 = X + (size_t)rowA1 * C;

    float4v acc[2][8];
#pragma unroll
    for (int rt = 0; rt < 2; ++rt)
#pragma unroll
        for (int ct = 0; ct < 8; ++ct) acc[rt][ct] = {0.f, 0.f, 0.f, 0.f};

#pragma unroll
    for (int ks = 0; ks < 4; ++ks) {
        const int kb = ks * 32 + lk * 8;
        float xr0[8], xr1[8];
        *(float4v*)&xr0[0] = *(const float4v*)(xp0 + kb);
        *(float4v*)&xr0[4] = *(const float4v*)(xp0 + kb + 4);
        *(float4v*)&xr1[0] = *(const float4v*)(xp1 + kb);
        *(float4v*)&xr1[4] = *(const float4v*)(xp1 + kb + 4);
        short8v ah0, al0, ah1, al1;
#pragma unroll
        for (int j = 0; j < 8; ++j) {
            unsigned short h0 = f2bf(xr0[j]);
            unsigned short h1 = f2bf(xr1[j]);
            ah0[j] = (short)h0;
            ah1[j] = (short)h1;
            al0[j] = (short)f2bf(xr0[j] - bf2f(h0));
            al1[j] = (short)f2bf(xr1[j] - bf2f(h1));
        }
#pragma unroll
        for (int ct = 0; ct < 8; ++ct) {
            short8v bh = *(const short8v*)&Whl[0][ct * 16 + lm][kb];
            short8v bl = *(const short8v*)&Whl[1][ct * 16 + lm][kb];
            acc[0][ct] = __builtin_amdgcn_mfma_f32_16x16x32_bf16(ah0, bh,
                                                                 acc[0][ct], 0, 0, 0);
            acc[0][ct] = __builtin_amdgcn_mfma_f32_16x16x32_bf16(al0, bh,
                                                                 acc[0][ct], 0, 0, 0);
            acc[0][ct] = __builtin_amdgcn_mfma_f32_16x16x32_bf16(ah0, bl,
                                                                 acc[0][ct], 0, 0, 0);
            acc[1][ct] = __builtin_amdgcn_mfma_f32_16x16x32_bf16(ah1, bh,
                                                                 acc[1][ct], 0, 0, 0);
            acc[1][ct] = __builtin_amdgcn_mfma_f32_16x16x32_bf16(al1, bh,
                                                                 acc[1][ct], 0, 0, 0);
            acc[1][ct] = __builtin_amdgcn_mfma_f32_16x16x32_bf16(ah1, bl,
                                                                 acc[1][ct], 0, 0, 0);
        }
    }

    float sc[2][4];
#pragma unroll
    for (int rt = 0; rt < 2; ++rt)
#pragma unroll
        for (int q = 0; q < 4; ++q) {
            int r = rbase + rt * 16 + lk * 4 + q;
            sc[rt][q] = invs[r < N ? r : N - 1];
        }
#pragma unroll
    for (int rt = 0; rt < 2; ++rt)
#pragma unroll
        for (int ct = 0; ct < 8; ++ct)
#pragma unroll
            for (int q = 0; q < 4; ++q) {
                int r = rbase + rt * 16 + lk * 4 + q;
                if (r < N)
                    H[(size_t)r * C + ct * 16 + lm] =
                        f2bf(acc[rt][ct][q] * sc[rt][q]);
            }
}

// ---------------------------------------------------------------------------
// Kernel 2: canonical gather + ELU. Round-10 evidence: bytes-proportional at
// ~7.5 TB/s across MLP-1 and MLP-16 configs -> test the issue-rate component
// by halving instruction count and doubling in-flight bytes: 16 B/lane
// (ushort8), 16 lanes/row, 16 nodes/block, batch-16 (64 VGPR in flight, no
// launch_bounds min-wave cap -> no spill). Same bytes, same summation order.
// ---------------------------------------------------------------------------
__global__ __launch_bounds__(256) void gather_elu_kernel(
    const unsigned short* __restrict__ H, const int* __restrict__ edge,
    const float* __restrict__ invs, float* __restrict__ out, int N) {
    __shared__ int idx_s[16][K];

    const int t = threadIdx.x;
    const int g = t >> 4;
    const int l16 = t & 15;
    const int node = blockIdx.x * 16 + g;

    {   // stage 16 nodes x 32 edges = 512 ints: int2 per thread, coalesced
        int p = t * 2;
        int r = p >> 5;
        int c0 = p & 31;
        int nn = blockIdx.x * 16 + r;
        int2v e = {-1, -1};
        if (nn < N) e = *(const int2v*)(edge + (size_t)nn * K + c0);
        idx_s[r][c0] = e.x;
        idx_s[r][c0 + 1] = e.y;
    }
    __syncthreads();
    if (node >= N) return;

    const unsigned short* hp = H + l16 * 8;  // this lane's 8 channels
    float acc[8];
#pragma unroll
    for (int i = 0; i < 8; ++i) acc[i] = 0.f;

#pragma unroll
    for (int k0 = 0; k0 < K; k0 += 16) {
        ushort8v v[16];
#pragma unroll
        for (int u = 0; u < 16; ++u) {
            int j = idx_s[g][k0 + u];
            j = (j < 0) ? N : j;  // row N is all zeros
            v[u] = *(const ushort8v*)(hp + (size_t)j * C);
        }
#pragma unroll
        for (int u = 0; u < 16; ++u)
#pragma unroll
            for (int i = 0; i < 8; ++i) acc[i] += bf2f(v[u][i]);
    }

    ushort8v sv = *(const ushort8v*)(hp + (size_t)node * C);
    float s = invs[node];
    float r[8];
#pragma unroll
    for (int i = 0; i < 8; ++i) {
        float x = (acc[i] + bf2f(sv[i])) * s;
        r[i] = x > 0.f ? x : expm1f(x);
    }
    float* dst = out + (size_t)node * C + l16 * 8;
    float4v lo = {r[0], r[1], r[2], r[3]};
    float4v hi = {r[4], r[5], r[6], r[7]};
    *(float4v*)dst = lo;
    *(float4v*)(dst + 4) = hi;
}

}  // namespace

extern "C" void kernel_launch(void* const* d_in, const int* in_sizes, int n_in,
                              void* d_out, int out_size, void* d_ws, size_t ws_size,
                              hipStream_t stream) {
    const float* x = (const float*)d_in[0];
    const int* edge = (const int*)d_in[1];
    const float* W1 = (const float*)d_in[2];
    const float* W2 = (const float*)d_in[3];
    float* out = (float*)d_out;
    const int N = in_sizes[0] / C;  // 100000

    // Workspace: invs [N f32] | h [(N+1) x 128 bf16] | whl [2 x 2 x 16384 bf16]
    char* ws = (char*)d_ws;
    float* invs = (float*)ws;
    size_t invs_bytes = ((size_t)N * sizeof(float) + 255) & ~(size_t)255;
    unsigned short* h = (unsigned short*)(ws + invs_bytes);
    size_t h_bytes = (((size_t)(N + 1) * C * 2) + 255) & ~(size_t)255;
    unsigned short* whl = (unsigned short*)(ws + invs_bytes + h_bytes);

    const int degBlocks = (N + 31) / 32;      // also covers the 129 side-jobs
    const int gemmBlocks = (N + 127) / 128;
    const int gatherBlocks = (N + 15) / 16;

    deg_kernel<<<degBlocks, 256, 0, stream>>>(edge, invs, (unsigned int*)h, W1,
                                              W2, whl, N);
    // Layer 1: x -> h (bf16) -> act (fp32, in d_out)
    gemm_mfma_kernel<<<gemmBlocks, 256, 0, stream>>>(x, whl, invs, h, N);
    gather_elu_kernel<<<gatherBlocks, 256, 0, stream>>>(h, edge, invs, out, N);
    // Layer 2: act (d_out) -> h (bf16) -> out
    gemm_mfma_kernel<<<gemmBlocks, 256, 0, stream>>>(out, whl + 32768, invs, h, N);
    gather_elu_kernel<<<gatherBlocks, 256, 0, stream>>>(h, edge, invs, out, N);
}